// Round 1
// baseline (2034.087 us; speedup 1.0000x reference)
//
#include <hip/hip_runtime.h>
#include <stdint.h>

// VQEmbedding: z[B,2D] fp32, W_a/W_v [K,D] fp32.
// out0 = z_q_st [B,2D], out1 = z_q [B,2D] (identical values), out2 = scores [B,2K].
// Round 1: correctness-first fp32 path.
//   - fused NT-GEMM (128x128x16 tile, 8x8 microtile) + packed atomicMax argmax
//   - gather kernel writes both out0 and out1
// fp32 GEMM floor = 137.4 GF / 157 TF ~= 875us; this round targets ~1.2-1.8ms.

namespace {
constexpr int D     = 512;
constexpr int TWO_D = 1024;
constexpr int K     = 8192;   // codebook entries per half
constexpr int B     = 8192;   // batch

constexpr int BM = 128, BN = 128, BK = 16;
}

__global__ void init_ws_kernel(unsigned long long* __restrict__ ws) {
    int i = blockIdx.x * blockDim.x + threadIdx.x;
    if (i < 2 * B) ws[i] = 0ull;   // ws is re-poisoned 0xAA before every launch
}

// Monotonic float->uint key: orders like fp32 compare (handles sign).
__device__ __forceinline__ unsigned int score_key(float s) {
    unsigned int u = __float_as_uint(s);
    return (u & 0x80000000u) ? ~u : (u | 0x80000000u);
}

// packed = key<<32 | (0xFFFFFFFF - col)  -> atomicMax picks max score,
// and on exact fp32 ties the SMALLEST column index (jnp.argmax semantics).
__global__ __launch_bounds__(256, 2) void gemm_argmax_kernel(
    const float* __restrict__ z,      // [B, 2D]
    const float* __restrict__ Wa,     // [K, D]
    const float* __restrict__ Wv,     // [K, D]
    float* __restrict__ scores,       // [B, 2K]
    unsigned long long* __restrict__ ws)  // [2*B] packed argmax
{
    const int h = blockIdx.z;
    const float* __restrict__ W = (h == 0) ? Wa : Wv;
    const int rowBase = blockIdx.y * BM;
    const int colBase = blockIdx.x * BN;

    // +4 pad: keeps 16B alignment of rows (132*4=528B) and breaks bank aliasing
    __shared__ float As[BK][BM + 4];
    __shared__ float Bs[BK][BN + 4];

    const int tid = threadIdx.x;
    const int tx  = tid & 15;
    const int ty  = tid >> 4;

    float acc[8][8];
#pragma unroll
    for (int i = 0; i < 8; ++i)
#pragma unroll
        for (int j = 0; j < 8; ++j) acc[i][j] = 0.f;

    // staging: each thread loads 2 float4 per matrix per k-step
    const int lr = tid >> 2;         // 0..63
    const int lc = (tid & 3) * 4;    // 0,4,8,12

    const float* zBase = z + (size_t)rowBase * TWO_D + (size_t)h * D;
    const float* wBase = W + (size_t)colBase * D;

    for (int kt = 0; kt < D; kt += BK) {
        float4 a0 = *(const float4*)(zBase + (size_t)lr * TWO_D + kt + lc);
        float4 a1 = *(const float4*)(zBase + (size_t)(lr + 64) * TWO_D + kt + lc);
        float4 b0 = *(const float4*)(wBase + (size_t)lr * D + kt + lc);
        float4 b1 = *(const float4*)(wBase + (size_t)(lr + 64) * D + kt + lc);

        __syncthreads();   // previous iter's LDS reads must finish before overwrite

        As[lc + 0][lr] = a0.x; As[lc + 1][lr] = a0.y; As[lc + 2][lr] = a0.z; As[lc + 3][lr] = a0.w;
        As[lc + 0][lr + 64] = a1.x; As[lc + 1][lr + 64] = a1.y; As[lc + 2][lr + 64] = a1.z; As[lc + 3][lr + 64] = a1.w;
        Bs[lc + 0][lr] = b0.x; Bs[lc + 1][lr] = b0.y; Bs[lc + 2][lr] = b0.z; Bs[lc + 3][lr] = b0.w;
        Bs[lc + 0][lr + 64] = b1.x; Bs[lc + 1][lr + 64] = b1.y; Bs[lc + 2][lr + 64] = b1.z; Bs[lc + 3][lr + 64] = b1.w;

        __syncthreads();

#pragma unroll
        for (int k = 0; k < BK; ++k) {
            float4 A0 = *(const float4*)&As[k][ty * 4];
            float4 A1 = *(const float4*)&As[k][64 + ty * 4];
            float4 B0 = *(const float4*)&Bs[k][tx * 4];
            float4 B1 = *(const float4*)&Bs[k][64 + tx * 4];
            float am[8] = {A0.x, A0.y, A0.z, A0.w, A1.x, A1.y, A1.z, A1.w};
            float bn[8] = {B0.x, B0.y, B0.z, B0.w, B1.x, B1.y, B1.z, B1.w};
#pragma unroll
            for (int i = 0; i < 8; ++i)
#pragma unroll
                for (int j = 0; j < 8; ++j)
                    acc[i][j] = fmaf(am[i], bn[j], acc[i][j]);
        }
    }

    // epilogue: write scores (out2 layout [B, 2K], half h at col offset h*K)
    // and reduce per-row argmax.
#pragma unroll
    for (int i = 0; i < 8; ++i) {
        const int m = (i < 4) ? (ty * 4 + i) : (64 + ty * 4 + (i - 4));
        float* sp = scores + (size_t)(rowBase + m) * (2 * K) + (size_t)h * K + colBase;
        *(float4*)(sp + tx * 4)      = make_float4(acc[i][0], acc[i][1], acc[i][2], acc[i][3]);
        *(float4*)(sp + 64 + tx * 4) = make_float4(acc[i][4], acc[i][5], acc[i][6], acc[i][7]);

        unsigned long long best = 0ull;
#pragma unroll
        for (int j = 0; j < 8; ++j) {
            const int col = colBase + ((j < 4) ? (tx * 4 + j) : (64 + tx * 4 + (j - 4)));
            unsigned long long p =
                ((unsigned long long)score_key(acc[i][j]) << 32) |
                (unsigned long long)(0xFFFFFFFFu - (unsigned)col);
            best = (p > best) ? p : best;
        }
        // butterfly reduce across the 16 tx-lanes (tid bits 0..3)
#pragma unroll
        for (int w = 1; w < 16; w <<= 1) {
            unsigned int hi = (unsigned int)(best >> 32);
            unsigned int lo = (unsigned int)best;
            unsigned int ohi = __shfl_xor(hi, w, 64);
            unsigned int olo = __shfl_xor(lo, w, 64);
            unsigned long long o = ((unsigned long long)ohi << 32) | olo;
            if (o > best) best = o;
        }
        if (tx == 0)
            atomicMax(&ws[(size_t)h * B + rowBase + m], best);
    }
}

__global__ __launch_bounds__(256) void gather_kernel(
    const float* __restrict__ Wa, const float* __restrict__ Wv,
    const unsigned long long* __restrict__ ws,
    float* __restrict__ out0, float* __restrict__ out1)
{
    const int b = blockIdx.x;
    const int t = threadIdx.x;
    const unsigned int ia = 0xFFFFFFFFu - (unsigned int)(ws[b] & 0xFFFFFFFFull);
    const unsigned int iv = 0xFFFFFFFFu - (unsigned int)(ws[B + b] & 0xFFFFFFFFull);

    const float* src;
    size_t dst;
    if (t < 128) {
        src = Wa + (size_t)ia * D + t * 4;
        dst = (size_t)b * TWO_D + t * 4;
    } else {
        src = Wv + (size_t)iv * D + (t - 128) * 4;
        dst = (size_t)b * TWO_D + D + (t - 128) * 4;
    }
    float4 v = *(const float4*)src;
    *(float4*)(out0 + dst) = v;
    *(float4*)(out1 + dst) = v;
}

extern "C" void kernel_launch(void* const* d_in, const int* in_sizes, int n_in,
                              void* d_out, int out_size, void* d_ws, size_t ws_size,
                              hipStream_t stream) {
    const float* z  = (const float*)d_in[0];
    const float* Wa = (const float*)d_in[1];
    const float* Wv = (const float*)d_in[2];

    float* out0   = (float*)d_out;                       // z_q_x_st [B,2D]
    float* out1   = out0 + (size_t)B * TWO_D;            // z_q_x    [B,2D]
    float* scores = out1 + (size_t)B * TWO_D;            // indices  [B,2K]

    unsigned long long* ws = (unsigned long long*)d_ws;  // 2*B*8 = 128 KB

    hipLaunchKernelGGL(init_ws_kernel, dim3((2 * B + 255) / 256), dim3(256), 0, stream, ws);
    hipLaunchKernelGGL(gemm_argmax_kernel, dim3(K / BN, B / BM, 2), dim3(256), 0, stream,
                       z, Wa, Wv, scores, ws);
    hipLaunchKernelGGL(gather_kernel, dim3(B), dim3(256), 0, stream, Wa, Wv, ws, out0, out1);
}